// Round 7
// baseline (815.191 us; speedup 1.0000x reference)
//
#include <hip/hip_runtime.h>
#include <math.h>

#define R_ 512
#define C_ 512
#define E_ 256
#define H_ 8
#define D_ 32
#define RC_ (R_*C_)   // 262144
#define RP 136        // repack pitch (ushorts)

typedef __attribute__((ext_vector_type(8))) short bf16x8;
typedef __attribute__((ext_vector_type(4))) float f32x4;

__device__ __forceinline__ ushort f2bf(float f) {
    union { float f; unsigned u; } v; v.f = f;
    unsigned r = v.u + 0x7FFFu + ((v.u >> 16) & 1u);   // RNE
    return (ushort)(r >> 16);
}
__device__ __forceinline__ float bf2f(ushort u) {
    union { unsigned u; float f; } v; v.u = ((unsigned)u) << 16;
    return v.f;
}

// 16B global->LDS direct copy (lane-linear dest), fallback = reg staging.
__device__ __forceinline__ void gll16(const ushort* g, ushort* l) {
#if __has_builtin(__builtin_amdgcn_global_load_lds)
    __builtin_amdgcn_global_load_lds(
        (const __attribute__((address_space(1))) unsigned*)(unsigned long long)g,
        (__attribute__((address_space(3))) unsigned*)(unsigned)(unsigned long long)l,
        16, 0, 0);
#else
    *(uint4*)l = *(const uint4*)g;
#endif
}

// Stage one 16B chunk f of a [rows][32-ushort] tile.  Source slot is XOR-
// swizzled with (row>>1)&3 (the bank-relevant key for 64B rows: bank base
// alternates with row&1, so row>>1 spreads the remaining aliasing).  LDS
// dest stays lane-linear (gll requirement); the read side applies the same
// involution.
#define SCH(gbase, stride, lds, f)                                               \
    gll16((gbase) + (size_t)((f) >> 2) * (stride)                                \
              + (((((f) & 3) ^ ((((f) >> 2) >> 1) & 3))) << 3),                  \
          (lds) + (f) * 8)

// Per-wave 64x64 output, 16x16x32 bf16 MFMA, K=32 per step, 32-ushort rows.
#define PREAMBLE(WM, WN)                                \
    const int t = threadIdx.x;                          \
    const int wid = t >> 6, l = t & 63;                 \
    const int wm = (WM), wn = (WN);                     \
    const int l15 = l & 15, lhi = l >> 4;               \
    const int swz8 = (lhi ^ ((l15 >> 1) & 3)) * 8;      \
    f32x4 acc[4][4];                                    \
    _Pragma("unroll")                                   \
    for (int a_ = 0; a_ < 4; ++a_)                      \
        _Pragma("unroll")                               \
        for (int b_ = 0; b_ < 4; ++b_)                  \
            acc[a_][b_] = (f32x4){0.f, 0.f, 0.f, 0.f};

#define MFMA_STEP(As, Bs)                                                        \
    {                                                                            \
        bf16x8 af_[4], bf_[4];                                                   \
        _Pragma("unroll")                                                        \
        for (int f_ = 0; f_ < 4; ++f_) {                                         \
            af_[f_] = *(const bf16x8*)((As) + (wm*64 + f_*16 + l15)*32 + swz8);  \
            bf_[f_] = *(const bf16x8*)((Bs) + (wn*64 + f_*16 + l15)*32 + swz8);  \
        }                                                                        \
        _Pragma("unroll")                                                        \
        for (int m_ = 0; m_ < 4; ++m_)                                           \
            _Pragma("unroll")                                                    \
            for (int n_ = 0; n_ < 4; ++n_)                                       \
                acc[m_][n_] = __builtin_amdgcn_mfma_f32_16x16x32_bf16(           \
                    af_[m_], bf_[n_], acc[m_][n_], 0, 0, 0);                     \
    }

// Double-buffered K-loop, __syncthreads-fenced (safe: full vmcnt/lgkm drain
// before each barrier).  Loads for tile t+1 issue before tile t's compute.
// Trailing sync protects the repack alias of the staging buffers.
#define DBUF(STG, NIT)                                                           \
    STG(0, A0, B0); __syncthreads();                                             \
    for (int itp = 0; itp < (NIT)/2 - 1; ++itp) {                                \
        STG(2*itp+1, A1, B1); MFMA_STEP(A0, B0); __syncthreads();                \
        STG(2*itp+2, A0, B0); MFMA_STEP(A1, B1); __syncthreads();                \
    }                                                                            \
    STG((NIT)-1, A1, B1); MFMA_STEP(A0, B0); __syncthreads();                    \
    MFMA_STEP(A1, B1); __syncthreads();

// ---------------------------------------------------------------------------
// x fp32 -> bf16, once.
// ---------------------------------------------------------------------------
__global__ __launch_bounds__(256) void convert_x(
    const float* __restrict__ x, ushort* __restrict__ xb)
{
    const size_t blk = (size_t)blockIdx.x * 4096;
    #pragma unroll
    for (int c = 0; c < 4; ++c) {
        const size_t s = blk + ((size_t)threadIdx.x + 256 * c) * 4;
        float4 a = *(const float4*)(x + s);
        ushort o[4] = {f2bf(a.x), f2bf(a.y), f2bf(a.z), f2bf(a.w)};
        *(uint2*)(xb + s) = *(uint2*)o;
    }
}

// ---------------------------------------------------------------------------
// Weights -> n-major bf16.
// ---------------------------------------------------------------------------
__global__ __launch_bounds__(256) void convert_w(
    const float* __restrict__ Wq, const float* __restrict__ Wk,
    const float* __restrict__ Wv, const float* __restrict__ Wo,
    ushort* __restrict__ WTqkv, ushort* __restrict__ WoT)
{
    const int id = blockIdx.x;      // 0..1023
    const int matn = id >> 8;
    const int n = id & 255;
    const int k = threadIdx.x;
    const float* W = (matn == 0) ? Wq : (matn == 1) ? Wk : (matn == 2) ? Wv : Wo;
    ushort v = f2bf(W[(size_t)k * E_ + n]);
    if (matn < 3) WTqkv[((size_t)matn * E_ + n) * E_ + k] = v;
    else          WoT[(size_t)n * E_ + k] = v;
}

// ---------------------------------------------------------------------------
// Fused QKV projection.  BM=256 x BN=128, 512 threads (8 waves 4x2), BK=32,
// 6144 blocks XCD-chunked, nt fastest (6 blocks sharing an x panel per XCD).
// Epilogue: 2 phases of 128 rows through the aliased LDS; v transposed.
// ---------------------------------------------------------------------------
__global__ __launch_bounds__(512) void qkv_mfma(
    const ushort* __restrict__ xb, const ushort* __restrict__ WT,
    const float* __restrict__ bq, const float* __restrict__ bk,
    const float* __restrict__ bv, const float* __restrict__ mask,
    ushort* __restrict__ qb, ushort* __restrict__ kb, ushort* __restrict__ vb)
{
    __shared__ __align__(16) ushort S[24576];   // 48 KB: staging dbuf + repack
    ushort* A0 = S;            // 256x32
    ushort* A1 = S + 8192;
    ushort* B0 = S + 16384;    // 128x32
    ushort* B1 = S + 20480;
    const int id = ((blockIdx.x & 7) * 768) + (blockIdx.x >> 3);
    const int nt = id % 6;
    const int rc0 = (id / 6) * 256;
    PREAMBLE(wid >> 1, wid & 1);

    const ushort* Ab = xb + (size_t)rc0 * E_;
    const ushort* Bb = WT + (size_t)nt * 128 * E_;

#define QSTG(i, Abuf, Bbuf) {                                   \
    const ushort* Ai = Ab + (i) * 32;                           \
    const ushort* Bi = Bb + (i) * 32;                           \
    SCH(Ai, E_, Abuf, t); SCH(Ai, E_, Abuf, t + 512);           \
    SCH(Bi, E_, Bbuf, t); }
    DBUF(QSTG, 8);

    const int proj = nt >> 1;
    const float* bias = (proj == 0) ? bq : (proj == 1) ? bk : bv;
    float bvv[4];
    #pragma unroll
    for (int fn = 0; fn < 4; ++fn)
        bvv[fn] = bias[(nt * 128 + wn * 64 + fn * 16 + l15) & 255];

    #pragma unroll
    for (int p = 0; p < 2; ++p) {
        if ((wm >> 1) == p) {
            const int mloc = (wm & 1) * 64;
            #pragma unroll
            for (int fm = 0; fm < 4; ++fm)
                #pragma unroll
                for (int fn = 0; fn < 4; ++fn)
                    #pragma unroll
                    for (int rg = 0; rg < 4; ++rg) {
                        const int m = mloc + fm * 16 + lhi * 4 + rg;
                        const int n = wn * 64 + fn * 16 + l15;
                        const ushort val = f2bf(acc[fm][fn][rg] + bvv[fn]);
                        if (proj < 2) S[m * RP + n] = val;
                        else          S[n * RP + m] = val;
                    }
        }
        __syncthreads();
        const int rcb = rc0 + p * 128;
        const int r = rcb >> 9, c0 = rcb & 511;
        if (proj < 2) {
            ushort* dst = (proj == 0) ? qb : kb;
            #pragma unroll
            for (int c = 0; c < 4; ++c) {
                const int idx = t + 512 * c;
                const int mrow = idx >> 4, ne = (idx & 15) * 8;
                uint4 w = *(const uint4*)(S + mrow * RP + ne);
                if (proj == 0) {   // q: * 1/128 * (1-mask)
                    const float sk = 0.0078125f * (1.0f - mask[rcb + mrow]);
                    ushort* ws = (ushort*)&w;
                    #pragma unroll
                    for (int jj = 0; jj < 8; ++jj) ws[jj] = f2bf(bf2f(ws[jj]) * sk);
                }
                const int e = (nt & 1) * 128 + ne, h = e >> 5, d = e & 31;
                *(uint4*)(dst + ((((size_t)h * R_ + r) * C_) + c0 + mrow) * D_ + d) = w;
            }
        } else {
            #pragma unroll
            for (int c = 0; c < 4; ++c) {
                const int idx = t + 512 * c;
                const int nrow = idx >> 4, m0 = (idx & 15) * 8;
                uint4 w = *(const uint4*)(S + nrow * RP + m0);
                const int e = (nt & 1) * 128 + nrow, h = e >> 5, d = e & 31;
                *(uint4*)(vb + (((size_t)h * R_ + r) * D_ + d) * C_ + c0 + m0) = w;
            }
        }
        __syncthreads();
    }
}

// ---------------------------------------------------------------------------
// Attention logits.  128x128 tile, 256 threads, K split 8-way (1024 blocks).
// ---------------------------------------------------------------------------
__global__ __launch_bounds__(256) void logits_mfma(
    const ushort* __restrict__ qb, const ushort* __restrict__ kb,
    float* __restrict__ partial)
{
    __shared__ __align__(16) ushort S[16384];
    ushort* A0 = S;
    ushort* B0 = S + 4096;
    ushort* A1 = S + 8192;
    ushort* B1 = S + 12288;
    const int id = ((blockIdx.x & 7) * 128) + (blockIdx.x >> 3);
    const int sub = id & 15;
    const int j0 = (sub & 3) * 128;         // j fastest: 4 blocks share q panel
    const int i0 = (sub >> 2) * 128;
    const int hks = id >> 4;                // 0..63
    const int h = hks >> 3, ks = hks & 7;
    PREAMBLE(wid >> 1, wid & 1);

    const ushort* Ab = qb + (((size_t)h * R_ + ks * 64) * C_ + i0) * D_;
    const ushort* Bb = kb + (((size_t)h * R_ + ks * 64) * C_ + j0) * D_;

#define LSTG(i, Abuf, Bbuf) {                                   \
    const ushort* Ai = Ab + (size_t)(i) * (C_ * D_);            \
    const ushort* Bi = Bb + (size_t)(i) * (C_ * D_);            \
    SCH(Ai, D_, Abuf, t); SCH(Ai, D_, Abuf, t + 256);           \
    SCH(Bi, D_, Bbuf, t); SCH(Bi, D_, Bbuf, t + 256); }
    DBUF(LSTG, 64);

    float* dst = partial + ((size_t)ks * H_ + h) * C_ * C_;
    #pragma unroll
    for (int fm = 0; fm < 4; ++fm)
        #pragma unroll
        for (int rg = 0; rg < 4; ++rg) {
            const int i = i0 + wm * 64 + fm * 16 + lhi * 4 + rg;
            #pragma unroll
            for (int fn = 0; fn < 4; ++fn) {
                const int j = j0 + wn * 64 + fn * 16 + l15;
                dst[(size_t)i * C_ + j] = acc[fm][fn][rg];
            }
        }
}

// ---------------------------------------------------------------------------
// Sum 8 K-split partials + i-axis mask + softmax over j.
// ---------------------------------------------------------------------------
__global__ __launch_bounds__(256) void softmax_kernel(
    const float* __restrict__ partial, const float* __restrict__ mask,
    float* __restrict__ probs, ushort* __restrict__ Pb)
{
    const int hi = blockIdx.x;
    const int i = hi & 511;
    const int t = threadIdx.x;
    const size_t base = (size_t)hi * C_;
    const size_t stride = (size_t)H_ * C_ * C_;
    float v0 = 0.f, v1 = 0.f;
    #pragma unroll
    for (int ksp = 0; ksp < 8; ++ksp) {
        v0 += partial[ksp * stride + base + t];
        v1 += partial[ksp * stride + base + t + 256];
    }
    const float mi = mask[i];
    const float keep = 1.0f - mi;
    v0 = v0 * keep + mi * (-10000.0f);
    v1 = v1 * keep + mi * (-10000.0f);

    float m = fmaxf(v0, v1);
    #pragma unroll
    for (int off = 32; off > 0; off >>= 1) m = fmaxf(m, __shfl_xor(m, off));
    __shared__ float red[4];
    if ((t & 63) == 0) red[t >> 6] = m;
    __syncthreads();
    m = fmaxf(fmaxf(red[0], red[1]), fmaxf(red[2], red[3]));

    const float e0 = expf(v0 - m), e1 = expf(v1 - m);
    float s = e0 + e1;
    #pragma unroll
    for (int off = 32; off > 0; off >>= 1) s += __shfl_xor(s, off);
    __syncthreads();
    if ((t & 63) == 0) red[t >> 6] = s;
    __syncthreads();
    s = red[0] + red[1] + red[2] + red[3];

    const float inv = 1.0f / s;
    const float p0 = e0 * inv, p1 = e1 * inv;
    probs[base + t] = p0;
    probs[base + t + 256] = p1;
    Pb[base + t] = f2bf(p0);
    Pb[base + t + 256] = f2bf(p1);
}

// ---------------------------------------------------------------------------
// Context.  BM=128 (i) x BN=256 (n=(r,d)), 512 threads (8 waves 2x4), BK=32.
// 2048 blocks; one head per XCD; i fastest (4 blocks share a vb panel).
// ---------------------------------------------------------------------------
__global__ __launch_bounds__(512) void context_mfma(
    const ushort* __restrict__ Pb, const ushort* __restrict__ vb,
    ushort* __restrict__ ctxb)
{
    __shared__ __align__(16) ushort S[24576];
    ushort* A0 = S;            // 128x32
    ushort* A1 = S + 4096;
    ushort* B0 = S + 8192;     // 256x32
    ushort* B1 = S + 16384;
    const int id = ((blockIdx.x & 7) * 256) + (blockIdx.x >> 3);
    const int i0 = (id & 3) * 128;
    const int n0 = ((id >> 2) & 63) * 256;
    const int h = id >> 8;
    PREAMBLE(wid >> 2, wid & 3);

    const ushort* Ab = Pb + ((size_t)h * C_ + i0) * C_;
    const ushort* Bb = vb + ((size_t)h * R_ * D_ + n0) * C_;

#define CSTG(i, Abuf, Bbuf) {                                   \
    const ushort* Ai = Ab + (i) * 32;                           \
    const ushort* Bi = Bb + (i) * 32;                           \
    SCH(Ai, C_, Abuf, t);                                       \
    SCH(Bi, C_, Bbuf, t); SCH(Bi, C_, Bbuf, t + 512); }
    DBUF(CSTG, 16);

    #pragma unroll
    for (int p = 0; p < 2; ++p) {
        if ((wn >> 1) == p) {
            #pragma unroll
            for (int fm = 0; fm < 4; ++fm)
                #pragma unroll
                for (int fn = 0; fn < 4; ++fn)
                    #pragma unroll
                    for (int rg = 0; rg < 4; ++rg) {
                        const int m = wm * 64 + fm * 16 + lhi * 4 + rg;
                        const int nloc = (wn & 1) * 64 + fn * 16 + l15;
                        S[m * RP + nloc] = f2bf(acc[fm][fn][rg]);
                    }
        }
        __syncthreads();
        #pragma unroll
        for (int c = 0; c < 4; ++c) {
            const int idx = t + 512 * c;
            const int mrow = idx >> 4, nl = (idx & 15) * 8;
            uint4 w = *(const uint4*)(S + mrow * RP + nl);
            const int n = n0 + p * 128 + nl;
            const int rr = n >> 5, d = n & 31;
            const size_t rc = (size_t)rr * C_ + i0 + mrow;
            *(uint4*)(ctxb + rc * E_ + h * D_ + d) = w;
        }
        __syncthreads();
    }
}

// ---------------------------------------------------------------------------
// Output projection.  BM=256 x BN=128, 512 threads (8 waves 4x2), fp32 out.
// Epilogue: 4 phases (2 m-halves x 2 fn-halves) through Sf[128][68].
// ---------------------------------------------------------------------------
__global__ __launch_bounds__(512) void out_proj_mfma(
    const ushort* __restrict__ ctxb, const ushort* __restrict__ WoT,
    const float* __restrict__ bo, float* __restrict__ out)
{
    __shared__ __align__(16) ushort S[24576];
    ushort* A0 = S;            // 256x32
    ushort* A1 = S + 8192;
    ushort* B0 = S + 16384;    // 128x32
    ushort* B1 = S + 20480;
    float* Sf = (float*)S;     // 128x68 fp32 repack
    const int id = ((blockIdx.x & 7) * 256) + (blockIdx.x >> 3);
    const int n0 = (id & 1) * 128;
    const int rc0 = (id >> 1) * 256;
    PREAMBLE(wid >> 1, wid & 1);

    const ushort* Ab = ctxb + (size_t)rc0 * E_;
    const ushort* Bb = WoT + (size_t)n0 * E_;

#define OSTG(i, Abuf, Bbuf) {                                   \
    const ushort* Ai = Ab + (i) * 32;                           \
    const ushort* Bi = Bb + (i) * 32;                           \
    SCH(Ai, E_, Abuf, t); SCH(Ai, E_, Abuf, t + 512);           \
    SCH(Bi, E_, Bbuf, t); }
    DBUF(OSTG, 8);

    float bvv[4];
    #pragma unroll
    for (int fn = 0; fn < 4; ++fn)
        bvv[fn] = bo[n0 + wn * 64 + fn * 16 + l15];

    #pragma unroll
    for (int p = 0; p < 2; ++p) {
        #pragma unroll
        for (int q = 0; q < 2; ++q) {
            if ((wm >> 1) == p) {
                const int mloc = (wm & 1) * 64;
                #pragma unroll
                for (int fm = 0; fm < 4; ++fm)
                    #pragma unroll
                    for (int fh = 0; fh < 2; ++fh) {
                        const int fn = 2 * q + fh;
                        #pragma unroll
                        for (int rg = 0; rg < 4; ++rg) {
                            const int m = mloc + fm * 16 + lhi * 4 + rg;
                            const int s = wn * 32 + fh * 16 + l15;
                            Sf[m * 68 + s] = acc[fm][fn][rg] + bvv[fn];
                        }
                    }
            }
            __syncthreads();
            #pragma unroll
            for (int c = 0; c < 4; ++c) {
                const int idx = t + 512 * c;
                const int row = idx >> 4, s0 = (idx & 15) * 4;
                float4 w = *(const float4*)(Sf + row * 68 + s0);
                const int ncol = n0 + (s0 >> 5) * 64 + (2 * q + ((s0 >> 4) & 1)) * 16 + (s0 & 15);
                *(float4*)(out + ((size_t)rc0 + p * 128 + row) * E_ + ncol) = w;
            }
            __syncthreads();
        }
    }
}

// ---------------------------------------------------------------------------
extern "C" void kernel_launch(void* const* d_in, const int* in_sizes, int n_in,
                              void* d_out, int out_size, void* d_ws, size_t ws_size,
                              hipStream_t stream)
{
    const float* x    = (const float*)d_in[0];
    const float* mask = (const float*)d_in[1];
    const float* Wq   = (const float*)d_in[2];
    const float* bq   = (const float*)d_in[3];
    const float* Wk   = (const float*)d_in[4];
    const float* bk   = (const float*)d_in[5];
    const float* Wv   = (const float*)d_in[6];
    const float* bv   = (const float*)d_in[7];
    const float* Wo   = (const float*)d_in[8];
    const float* bo   = (const float*)d_in[9];

    float* out   = (float*)d_out;                       // [R,C,E] fp32
    float* probs = out + (size_t)RC_ * E_;              // [H,C,C] fp32

    char* ws = (char*)d_ws;
    ushort* qb      = (ushort*)(ws);                    // 128 MB  [h][r][c][d]
    ushort* kb      = (ushort*)(ws + 134217728ull);     // 128 MB  [h][r][c][d]
    ushort* vb      = (ushort*)(ws + 268435456ull);     // 128 MB  [h][r][d][c]
    ushort* ctxb    = (ushort*)(ws + 402653184ull);     // 128 MB  [rc][e]
    float*  partial = (float*)(ws + 536870912ull);      // 64 MB   [8][h][i][j]
    ushort* Pb      = (ushort*)(ws + 603979776ull);     // 4 MB    [h][i][j]
    ushort* WTqkv   = (ushort*)(ws + 608174080ull);     // 384 KB
    ushort* WoT     = (ushort*)(ws + 608567296ull);     // 128 KB
    ushort* xb      = (ushort*)(ws + 608700416ull);     // 128 MB  [rc][e]

    convert_x<<<16384, 256, 0, stream>>>(x, xb);
    convert_w<<<1024, 256, 0, stream>>>(Wq, Wk, Wv, Wo, WTqkv, WoT);
    qkv_mfma<<<6144, 512, 0, stream>>>(xb, WTqkv, bq, bk, bv, mask, qb, kb, vb);
    logits_mfma<<<1024, 256, 0, stream>>>(qb, kb, partial);
    softmax_kernel<<<4096, 256, 0, stream>>>(partial, mask, probs, Pb);
    context_mfma<<<2048, 512, 0, stream>>>(Pb, vb, ctxb);
    out_proj_mfma<<<2048, 512, 0, stream>>>(ctxb, WoT, bo, out);
}